// Round 5
// baseline (65.165 us; speedup 1.0000x reference)
//
#include <hip/hip_runtime.h>
#include <hip/hip_bf16.h>

// Problem constants (from reference)
#define BB 8
#define CC 64
#define OO 64
#define HH 128
#define WW 128
#define HP 130   // padded
#define WP 130
#define KP 9

typedef __attribute__((ext_vector_type(8))) short bf16x8;
typedef __attribute__((ext_vector_type(4))) float f32x4;
typedef __attribute__((ext_vector_type(2))) unsigned u32x2;
typedef __attribute__((ext_vector_type(4))) unsigned u32x4;

static __device__ __forceinline__ unsigned short f2bf(float f) {
  unsigned u = __float_as_uint(f);
  unsigned r = u + 0x7fffu + ((u >> 16) & 1u);
  return (unsigned short)(r >> 16);
}
static __device__ __forceinline__ f32x4 unpk4(unsigned lo, unsigned hi) {
  f32x4 r;
  r.x = __uint_as_float(lo << 16);
  r.y = __uint_as_float(lo & 0xffff0000u);
  r.z = __uint_as_float(hi << 16);
  r.w = __uint_as_float(hi & 0xffff0000u);
  return r;
}

// ---------------------------------------------------------------------------
// Kernel 1: x [B][C][H][W] f32 -> x_t [B][HP][WP][C] bf16, zero borders.
// XCD-swizzled so XCD k produces x_t[b=k] into its own L2.
// ---------------------------------------------------------------------------
__global__ __launch_bounds__(256) void k_xpose(const float* __restrict__ x,
                                               unsigned short* __restrict__ xt) {
  __shared__ unsigned short tile[128][66];
  int wg0 = blockIdx.x;           // B*H = 1024
  int wg = (wg0 & 7) * 128 + (wg0 >> 3);   // XCD-chunked: XCD k gets b=k
  int h = wg & 127, b = wg >> 7;
  int t = threadIdx.x;
  int w = t & 127, chalf = t >> 7;
  const float* xp = x + ((size_t)(b * CC) * HH + h) * WW;
#pragma unroll 4
  for (int c2 = 0; c2 < 32; ++c2) {
    int c = c2 * 2 + chalf;
    float v = xp[(size_t)c * HH * WW + w];
    tile[w][c] = f2bf(v);
  }
  __syncthreads();
  int c = t & 63, w2 = t >> 6;
  unsigned short* xtb = xt + (size_t)b * HP * WP * CC;
#pragma unroll 4
  for (int w4 = 0; w4 < 32; ++w4) {
    int ww = w4 * 4 + w2;
    xtb[((size_t)(h + 1) * WP + (ww + 1)) * CC + c] = tile[ww][c];
  }
  if (t < 128) {
    int xx = (t >= 64) ? (WP - 1) : 0;
    xtb[((size_t)(h + 1) * WP + xx) * CC + (t & 63)] = 0;
  }
  if (h == 0) {
    for (int i = t; i < 2 * WP * CC; i += 256) {
      int top = (i < WP * CC);
      int rem = top ? i : i - WP * CC;
      size_t y = top ? 0 : (HP - 1);
      xtb[y * WP * CC + rem] = 0;
    }
  }
}

// ---------------------------------------------------------------------------
// Kernel 2: weight -> bf16 MFMA B-fragments.
// byte(f, lane, j): f = (p*2+ks)*4+nf ; c = ks*32+(lane>>4)*8+j ; o = nf*16+(lane&15)
// ---------------------------------------------------------------------------
__global__ __launch_bounds__(256) void k_wfrag(const float* __restrict__ wsrc,
                                               unsigned short* __restrict__ wf) {
  int flat = blockIdx.x * 256 + threadIdx.x;
  int j = flat & 7;
  int lane = (flat >> 3) & 63;
  int nf = (flat >> 9) & 3;
  int ks = (flat >> 11) & 1;
  int p = flat >> 12;
  int c = ks * 32 + ((lane >> 4) * 8) + j;
  int o = nf * 16 + (lane & 15);
  wf[flat] = f2bf(wsrc[(size_t)(o * CC + c) * KP + p]);
}

// ---------------------------------------------------------------------------
// Main kernel. One wg = (b, h) full 128-px row x all 64 outputs. 4 waves.
// N-split MFMA (wave w -> outputs [16w,16w+16)), M=128 (8 m-tiles).
// BUILD lane split: c8 = lane&7 (8 channels, dwordx4), pg = lane>>3 (8 px).
// Double-buffered S -> ONE barrier per p; p+1 gathers in flight across it.
// ---------------------------------------------------------------------------
__global__ __launch_bounds__(256) void k_deform_main(const float* __restrict__ offset,
                                                     const float* __restrict__ bias,
                                                     const unsigned short* __restrict__ xt,
                                                     const unsigned short* __restrict__ wf,
                                                     float* __restrict__ out) {
  __shared__ __align__(16) char lds[51200];
  // [0,18432)   coords: 4 waves * 288 entries * 16B
  // [18432,51200) S double buffer: 2 x (128 px * 128 B, XOR-swizzled rows)
  // epilogue reuses [0,33280) as S2: f32 [128][65]
  int wg0 = blockIdx.x;                    // 1024
  int wgs = (wg0 & 7) * 128 + (wg0 >> 3);  // XCD k -> b=k
  int h = wgs & 127, b = wgs >> 7;
  int t = threadIdx.x, wave = t >> 6, lane = t & 63;

  uint4* coords = reinterpret_cast<uint4*>(lds) + wave * 288;
  char* S0 = lds + 18432;

  // ---- phase 1: coordinate precompute (288 (p,pxl) pairs / wave) ----
  // entry: { byte_off(corner00), wy1_bits, wx1_bits, dx | dy<<16 }
#pragma unroll
  for (int it = 0; it < 5; ++it) {
    int pair = it * 64 + lane;
    if (pair < 288) {
      int p = pair >> 5, pxl = pair & 31;
      int w = wave * 32 + pxl;             // global pixel x
      const float* offp = offset + (((size_t)b * 18 + 2 * p) * HH + h) * WW + w;
      float offy = offp[0];
      float offx = offp[HH * WW];
      float cy = (float)(h + p / 3) + offy;
      float cx = (float)(w + p % 3) + offx;
      float y0f = floorf(cy), x0f = floorf(cx);
      float wy1 = cy - y0f, wx1 = cx - x0f;
      int iy0 = (int)y0f, ix0 = (int)x0f;
      int iy0c = min(max(iy0, 0), HP - 1);
      int iy1c = min(max(iy0 + 1, 0), HP - 1);
      int ix0c = min(max(ix0, 0), WP - 1);
      int ix1c = min(max(ix0 + 1, 0), WP - 1);
      uint4 e;
      e.x = (unsigned)((iy0c * WP + ix0c) * (CC * 2));
      e.y = __float_as_uint(wy1);
      e.z = __float_as_uint(wx1);
      e.w = (unsigned)((ix1c - ix0c) * (CC * 2)) |
            ((unsigned)((iy1c - iy0c) * (WP * CC * 2)) << 16);
      coords[pair] = e;
    }
  }

  f32x4 acc[8];
#pragma unroll
  for (int m = 0; m < 8; ++m) acc[m] = (f32x4){0.f, 0.f, 0.f, 0.f};

  const char* xb = (const char*)(xt + (size_t)b * HP * WP * CC);
  int c8 = lane & 7, pg = lane >> 3;
  unsigned cb = (unsigned)c8 * 16;              // byte offset of this lane's 8 channels
  unsigned swz = cb ^ ((unsigned)pg << 4);      // write column (XOR row swizzle)
  const uint4* cwl = coords + pg;               // + p*32 + it*8

  auto LOADC = [&](int p, uint4* eo) {
#pragma unroll
    for (int it = 0; it < 4; ++it) eo[it] = cwl[p * 32 + it * 8];
  };
  auto ISSUE = [&](const uint4* ei, u32x4* go) {
#pragma unroll
    for (int it = 0; it < 4; ++it) {
      unsigned dx = ei[it].w & 0xffffu, dy = ei[it].w >> 16;
      unsigned a00 = ei[it].x + cb;
      go[it * 4 + 0] = *(const u32x4*)(xb + a00);
      go[it * 4 + 1] = *(const u32x4*)(xb + (a00 + dx));
      go[it * 4 + 2] = *(const u32x4*)(xb + (a00 + dy));
      go[it * 4 + 3] = *(const u32x4*)(xb + (a00 + dy + dx));
    }
  };
  auto BUILD = [&](const uint4* ei, const u32x4* gi, char* Sc) {
    char* swave = Sc + wave * 4096 + pg * 128;
#pragma unroll
    for (int it = 0; it < 4; ++it) {
      float wy1 = __uint_as_float(ei[it].y), wx1 = __uint_as_float(ei[it].z);
      u32x4 q00 = gi[it * 4 + 0], q01 = gi[it * 4 + 1];
      u32x4 q10 = gi[it * 4 + 2], q11 = gi[it * 4 + 3];
      // channels 0-3
      f32x4 a00 = unpk4(q00.x, q00.y), a01 = unpk4(q01.x, q01.y);
      f32x4 a10 = unpk4(q10.x, q10.y), a11 = unpk4(q11.x, q11.y);
      f32x4 topA = a00 + wx1 * (a01 - a00);
      f32x4 botA = a10 + wx1 * (a11 - a10);
      f32x4 sA = topA + wy1 * (botA - topA);
      // channels 4-7
      f32x4 b00 = unpk4(q00.z, q00.w), b01 = unpk4(q01.z, q01.w);
      f32x4 b10 = unpk4(q10.z, q10.w), b11 = unpk4(q11.z, q11.w);
      f32x4 topB = b00 + wx1 * (b01 - b00);
      f32x4 botB = b10 + wx1 * (b11 - b10);
      f32x4 sB = topB + wy1 * (botB - topB);
      unsigned r0, r1, r2, r3;
      asm("v_cvt_pk_bf16_f32 %0, %1, %2" : "=v"(r0) : "v"(sA.x), "v"(sA.y));
      asm("v_cvt_pk_bf16_f32 %0, %1, %2" : "=v"(r1) : "v"(sA.z), "v"(sA.w));
      asm("v_cvt_pk_bf16_f32 %0, %1, %2" : "=v"(r2) : "v"(sB.x), "v"(sB.y));
      asm("v_cvt_pk_bf16_f32 %0, %1, %2" : "=v"(r3) : "v"(sB.z), "v"(sB.w));
      u32x4 pk; pk.x = r0; pk.y = r1; pk.z = r2; pk.w = r3;
      *reinterpret_cast<u32x4*>(swave + it * 1024 + swz) = pk;
    }
  };
  auto MFMA = [&](int p, const char* Sc) {
    // B-frags for this wave's output slice (nf = wave): 2 x 16B loads
    const char* wfb = (const char*)wf + ((size_t)(p * 8 + wave) * 1024) + (size_t)lane * 16;
    bf16x8 b0 = *reinterpret_cast<const bf16x8*>(wfb);
    bf16x8 b1 = *reinterpret_cast<const bf16x8*>(wfb + 4096);
    int l15 = lane & 15, kc = (lane >> 4) * 16, sw = (lane & 7) << 4;
#pragma unroll
    for (int m = 0; m < 8; ++m) {
      int rb = (m * 16 + l15) * 128;
      bf16x8 a0 = *reinterpret_cast<const bf16x8*>(Sc + rb + (kc ^ sw));
      bf16x8 a1 = *reinterpret_cast<const bf16x8*>(Sc + rb + ((64 + kc) ^ sw));
      acc[m] = __builtin_amdgcn_mfma_f32_16x16x32_bf16(a0, b0, acc[m], 0, 0, 0);
      acc[m] = __builtin_amdgcn_mfma_f32_16x16x32_bf16(a1, b1, acc[m], 0, 0, 0);
    }
  };

  // ---- software-pipelined p-loop, ONE barrier per p (double-buffered S) ----
  uint4 e[4];
  u32x4 g[16];
  LOADC(0, e);
  ISSUE(e, g);
#pragma unroll
  for (int p = 0; p < 9; ++p) {
    char* Sc = S0 + (p & 1) * 16384;
    uint4 e2[4];
    u32x4 g2[16];
    if (p < 8) LOADC(p + 1, e2);     // ds_reads; latency covered by BUILD
    BUILD(e, g, Sc);                 // consumes gathers, writes own S slice
    asm volatile("s_waitcnt lgkmcnt(0)" ::: "memory");  // S writes + old reads drained
    __builtin_amdgcn_s_barrier();    // single barrier: S[p&1] ready, S[(p+1)&1] free
    if (p < 8) ISSUE(e2, g2);        // p+1 gathers in flight across MFMA
    MFMA(p, Sc);                     // reads all waves' S rows + own wf slice
    if (p < 8) {
#pragma unroll
      for (int i = 0; i < 4; ++i) e[i] = e2[i];
#pragma unroll
      for (int i = 0; i < 16; ++i) g[i] = g2[i];
    }
  }

  // ---- epilogue: LDS transpose for coalesced NCHW stores ----
  __syncthreads();  // all MFMA reads done before overwriting lds as S2
  float* S2 = reinterpret_cast<float*>(lds);
  int l15 = lane & 15;
#pragma unroll
  for (int m = 0; m < 8; ++m) {
#pragma unroll
    for (int i2 = 0; i2 < 4; ++i2) {
      int px = m * 16 + ((lane >> 4) * 4) + i2;
      int o = wave * 16 + l15;
      S2[px * 65 + o] = acc[m][i2];
    }
  }
  __syncthreads();
  {
    int px = t & 127, o2 = t >> 7;
    float* op = out + (((size_t)b * OO) * HH + h) * WW + px;
#pragma unroll
    for (int o4 = 0; o4 < 32; ++o4) {
      int o = o4 * 2 + o2;
      op[(size_t)o * HH * WW] = S2[px * 65 + o] + bias[o];
    }
  }
}

// ---------------------------------------------------------------------------
extern "C" void kernel_launch(void* const* d_in, const int* in_sizes, int n_in,
                              void* d_out, int out_size, void* d_ws, size_t ws_size,
                              hipStream_t stream) {
  const float* x = (const float*)d_in[0];
  const float* offset = (const float*)d_in[1];
  const float* weight = (const float*)d_in[2];
  const float* bias = (const float*)d_in[3];
  float* out = (float*)d_out;

  unsigned short* xt = (unsigned short*)d_ws;                       // 17,305,600 B
  unsigned short* wf = (unsigned short*)((char*)d_ws + 17305600);   //     73,728 B

  k_xpose<<<BB * HH, 256, 0, stream>>>(x, xt);
  k_wfrag<<<144, 256, 0, stream>>>(weight, wf);
  k_deform_main<<<BB * HH, 256, 0, stream>>>(offset, bias, xt, wf, out);
}

// Round 6
// 55.759 us; speedup vs baseline: 1.1687x; 1.1687x over previous
//
#include <hip/hip_runtime.h>
#include <hip/hip_bf16.h>

// Problem constants (from reference)
#define BB 8
#define CC 64
#define OO 64
#define HH 128
#define WW 128
#define HP 130   // padded
#define WP 130
#define KP 9

typedef __attribute__((ext_vector_type(8))) short bf16x8;
typedef __attribute__((ext_vector_type(4))) float f32x4;
typedef __attribute__((ext_vector_type(4))) unsigned u32x4;

static __device__ __forceinline__ unsigned short f2bf(float f) {
  unsigned u = __float_as_uint(f);
  unsigned r = u + 0x7fffu + ((u >> 16) & 1u);
  return (unsigned short)(r >> 16);
}
static __device__ __forceinline__ f32x4 unpk4(unsigned lo, unsigned hi) {
  f32x4 r;
  r.x = __uint_as_float(lo << 16);
  r.y = __uint_as_float(lo & 0xffff0000u);
  r.z = __uint_as_float(hi << 16);
  r.w = __uint_as_float(hi & 0xffff0000u);
  return r;
}

// ---------------------------------------------------------------------------
// Kernel 1: x [B][C][H][W] f32 -> x_t [B][HP][WP][C] bf16, zero borders.
// XCD-swizzled so XCD k produces x_t[b=k] into its own L2.
// ---------------------------------------------------------------------------
__global__ __launch_bounds__(256) void k_xpose(const float* __restrict__ x,
                                               unsigned short* __restrict__ xt) {
  __shared__ unsigned short tile[128][66];
  int wg0 = blockIdx.x;           // B*H = 1024
  int wg = (wg0 & 7) * 128 + (wg0 >> 3);   // XCD-chunked: XCD k gets b=k
  int h = wg & 127, b = wg >> 7;
  int t = threadIdx.x;
  int w = t & 127, chalf = t >> 7;
  const float* xp = x + ((size_t)(b * CC) * HH + h) * WW;
#pragma unroll 4
  for (int c2 = 0; c2 < 32; ++c2) {
    int c = c2 * 2 + chalf;
    float v = xp[(size_t)c * HH * WW + w];
    tile[w][c] = f2bf(v);
  }
  __syncthreads();
  int c = t & 63, w2 = t >> 6;
  unsigned short* xtb = xt + (size_t)b * HP * WP * CC;
#pragma unroll 4
  for (int w4 = 0; w4 < 32; ++w4) {
    int ww = w4 * 4 + w2;
    xtb[((size_t)(h + 1) * WP + (ww + 1)) * CC + c] = tile[ww][c];
  }
  if (t < 128) {
    int xx = (t >= 64) ? (WP - 1) : 0;
    xtb[((size_t)(h + 1) * WP + xx) * CC + (t & 63)] = 0;
  }
  if (h == 0) {
    for (int i = t; i < 2 * WP * CC; i += 256) {
      int top = (i < WP * CC);
      int rem = top ? i : i - WP * CC;
      size_t y = top ? 0 : (HP - 1);
      xtb[y * WP * CC + rem] = 0;
    }
  }
}

// ---------------------------------------------------------------------------
// Kernel 2: weight -> bf16 MFMA B-fragments.
// byte(f, lane, j): f = (p*2+ks)*4+nf ; c = ks*32+(lane>>4)*8+j ; o = nf*16+(lane&15)
// ---------------------------------------------------------------------------
__global__ __launch_bounds__(256) void k_wfrag(const float* __restrict__ wsrc,
                                               unsigned short* __restrict__ wf) {
  int flat = blockIdx.x * 256 + threadIdx.x;
  int j = flat & 7;
  int lane = (flat >> 3) & 63;
  int nf = (flat >> 9) & 3;
  int ks = (flat >> 11) & 1;
  int p = flat >> 12;
  int c = ks * 32 + ((lane >> 4) * 8) + j;
  int o = nf * 16 + (lane & 15);
  wf[flat] = f2bf(wsrc[(size_t)(o * CC + c) * KP + p]);
}

// ---------------------------------------------------------------------------
// Main kernel. One wg = (b, h) full 128-px row x all 64 outputs. 4 waves.
// N-split MFMA (wave w -> outputs [16w,16w+16)), M=128 (8 m-tiles).
// ALL loop VMEM is inline-asm with hand-counted vmcnt: 16 gathers (next p) +
// 2 wf loads (this p) stay in flight across the barrier and MFMA. The
// compiler sees no VMEM in the loop so it cannot emit a vmcnt(0) drain.
// ---------------------------------------------------------------------------
__global__ __launch_bounds__(256) void k_deform_main(const float* __restrict__ offset,
                                                     const float* __restrict__ bias,
                                                     const unsigned short* __restrict__ xt,
                                                     const unsigned short* __restrict__ wf,
                                                     float* __restrict__ out) {
  __shared__ __align__(16) char lds[51200];
  // [0,18432)   coords: 4 waves * 288 entries * 16B
  // [18432,51200) S double buffer: 2 x (128 px * 128 B, XOR-swizzled rows)
  // epilogue reuses [0,33280) as S2: f32 [128][65]
  int wg0 = blockIdx.x;                    // 1024
  int wgs = (wg0 & 7) * 128 + (wg0 >> 3);  // XCD k -> b=k
  int h = wgs & 127, b = wgs >> 7;
  int t = threadIdx.x, wave = t >> 6, lane = t & 63;

  uint4* coords = reinterpret_cast<uint4*>(lds) + wave * 288;
  char* S0 = lds + 18432;

  // ---- phase 1: coordinate precompute (288 (p,pxl) pairs / wave) ----
  // entry: { byte_off(corner00), wy1_bits, wx1_bits, dx | dy<<16 }
#pragma unroll
  for (int it = 0; it < 5; ++it) {
    int pair = it * 64 + lane;
    if (pair < 288) {
      int p = pair >> 5, pxl = pair & 31;
      int w = wave * 32 + pxl;             // global pixel x
      const float* offp = offset + (((size_t)b * 18 + 2 * p) * HH + h) * WW + w;
      float offy = offp[0];
      float offx = offp[HH * WW];
      float cy = (float)(h + p / 3) + offy;
      float cx = (float)(w + p % 3) + offx;
      float y0f = floorf(cy), x0f = floorf(cx);
      float wy1 = cy - y0f, wx1 = cx - x0f;
      int iy0 = (int)y0f, ix0 = (int)x0f;
      int iy0c = min(max(iy0, 0), HP - 1);
      int iy1c = min(max(iy0 + 1, 0), HP - 1);
      int ix0c = min(max(ix0, 0), WP - 1);
      int ix1c = min(max(ix0 + 1, 0), WP - 1);
      uint4 e;
      e.x = (unsigned)((iy0c * WP + ix0c) * (CC * 2));
      e.y = __float_as_uint(wy1);
      e.z = __float_as_uint(wx1);
      e.w = (unsigned)((ix1c - ix0c) * (CC * 2)) |
            ((unsigned)((iy1c - iy0c) * (WP * CC * 2)) << 16);
      coords[pair] = e;
    }
  }

  f32x4 acc[8];
#pragma unroll
  for (int m = 0; m < 8; ++m) acc[m] = (f32x4){0.f, 0.f, 0.f, 0.f};

  const char* xb = (const char*)(xt + (size_t)b * HP * WP * CC);
  int c8 = lane & 7, pg = lane >> 3;
  unsigned cb = (unsigned)c8 * 16;              // byte offset of this lane's 8 channels
  unsigned swz = cb ^ ((unsigned)pg << 4);      // write column (XOR row swizzle)
  const uint4* cwl = coords + pg;               // + p*32 + it*8

// asm SADDR-form loads: uniform SGPR base + 32-bit per-lane voffset.
#define GLOADX(dst, voff) \
  asm volatile("global_load_dwordx4 %0, %1, %2" \
               : "=v"(dst) : "v"(voff), "s"(xb) : "memory")
#define GLOADW(dst, voff) \
  asm volatile("global_load_dwordx4 %0, %1, %2" \
               : "=v"(dst) : "v"(voff), "s"(wf) : "memory")

  auto LOADC = [&](int p, uint4* eo) {
#pragma unroll
    for (int it = 0; it < 4; ++it) eo[it] = cwl[p * 32 + it * 8];
  };
  auto ISSUE = [&](const uint4* ei, u32x4* go) {
#pragma unroll
    for (int it = 0; it < 4; ++it) {
      unsigned dx = ei[it].w & 0xffffu, dy = ei[it].w >> 16;
      unsigned a00 = ei[it].x + cb;
      unsigned a01 = a00 + dx, a10 = a00 + dy, a11 = a10 + dx;
      GLOADX(go[it * 4 + 0], a00);
      GLOADX(go[it * 4 + 1], a01);
      GLOADX(go[it * 4 + 2], a10);
      GLOADX(go[it * 4 + 3], a11);
    }
  };
  auto BUILD = [&](const uint4* ei, const u32x4* gi, char* Sc) {
    char* swave = Sc + wave * 4096 + pg * 128;
#pragma unroll
    for (int it = 0; it < 4; ++it) {
      float wy1 = __uint_as_float(ei[it].y), wx1 = __uint_as_float(ei[it].z);
      u32x4 q00 = gi[it * 4 + 0], q01 = gi[it * 4 + 1];
      u32x4 q10 = gi[it * 4 + 2], q11 = gi[it * 4 + 3];
      f32x4 a00 = unpk4(q00.x, q00.y), a01 = unpk4(q01.x, q01.y);
      f32x4 a10 = unpk4(q10.x, q10.y), a11 = unpk4(q11.x, q11.y);
      f32x4 topA = a00 + wx1 * (a01 - a00);
      f32x4 botA = a10 + wx1 * (a11 - a10);
      f32x4 sA = topA + wy1 * (botA - topA);
      f32x4 b00 = unpk4(q00.z, q00.w), b01 = unpk4(q01.z, q01.w);
      f32x4 b10 = unpk4(q10.z, q10.w), b11 = unpk4(q11.z, q11.w);
      f32x4 topB = b00 + wx1 * (b01 - b00);
      f32x4 botB = b10 + wx1 * (b11 - b10);
      f32x4 sB = topB + wy1 * (botB - topB);
      unsigned r0, r1, r2, r3;
      asm("v_cvt_pk_bf16_f32 %0, %1, %2" : "=v"(r0) : "v"(sA.x), "v"(sA.y));
      asm("v_cvt_pk_bf16_f32 %0, %1, %2" : "=v"(r1) : "v"(sA.z), "v"(sA.w));
      asm("v_cvt_pk_bf16_f32 %0, %1, %2" : "=v"(r2) : "v"(sB.x), "v"(sB.y));
      asm("v_cvt_pk_bf16_f32 %0, %1, %2" : "=v"(r3) : "v"(sB.z), "v"(sB.w));
      u32x4 pk; pk.x = r0; pk.y = r1; pk.z = r2; pk.w = r3;
      *reinterpret_cast<u32x4*>(swave + it * 1024 + swz) = pk;
    }
  };
  auto MFMA = [&](const char* Sc, bf16x8 b0, bf16x8 b1) {
    int l15 = lane & 15, kc = (lane >> 4) * 16, sw = (lane & 7) << 4;
#pragma unroll
    for (int m = 0; m < 8; ++m) {
      int rb = (m * 16 + l15) * 128;
      bf16x8 a0 = *reinterpret_cast<const bf16x8*>(Sc + rb + (kc ^ sw));
      bf16x8 a1 = *reinterpret_cast<const bf16x8*>(Sc + rb + ((64 + kc) ^ sw));
      acc[m] = __builtin_amdgcn_mfma_f32_16x16x32_bf16(a0, b0, acc[m], 0, 0, 0);
      acc[m] = __builtin_amdgcn_mfma_f32_16x16x32_bf16(a1, b1, acc[m], 0, 0, 0);
    }
  };

  // ---- asm-pipelined p-loop: counted vmcnt, ping-pong reg buffers ----
  uint4 eA[4], eB[4];
  u32x4 gA[16], gB[16];
  LOADC(0, eA);
  ISSUE(eA, gA);                 // 16 gathers for p=0 in flight
#pragma unroll
  for (int p = 0; p < 9; ++p) {
    char* Sc = S0 + (p & 1) * 16384;
    uint4* EC = (p & 1) ? eB : eA;
    uint4* EN = (p & 1) ? eA : eB;
    u32x4* GC = (p & 1) ? gB : gA;
    u32x4* GN = (p & 1) ? gA : gB;
    // 1) wf fragment loads for this p (2 loads, newest in queue)
    bf16x8 bv0, bv1;
    unsigned wfo0 = (unsigned)((p * 8 + wave) * 1024 + lane * 16);
    unsigned wfo1 = wfo0 + 4096;
    GLOADW(bv0, wfo0);
    GLOADW(bv1, wfo1);
    // 2) coords for p+1 (LDS reads, lgkm-tracked by compiler)
    if (p < 8) LOADC(p + 1, EN);
    // 3) drain the 16 gathers for p; keep the 2 wf loads flying
    asm volatile("s_waitcnt vmcnt(2)" ::: "memory");
    __builtin_amdgcn_sched_barrier(0);
    // 4) bilinear + S write
    BUILD(EC, GC, Sc);
    // 5) S visible to all waves
    asm volatile("s_waitcnt lgkmcnt(0)" ::: "memory");
    __builtin_amdgcn_s_barrier();
    // 6) launch p+1 gathers — they fly across MFMA + next BUILD's VALU
    if (p < 8) {
      ISSUE(EN, GN);
      // 7) drain the 2 wf loads (oldest); leave 16 gathers in flight
      asm volatile("s_waitcnt vmcnt(16)" ::: "memory");
    } else {
      asm volatile("s_waitcnt vmcnt(0)" ::: "memory");
    }
    __builtin_amdgcn_sched_barrier(0);
    // 8) MFMA for this p
    MFMA(Sc, bv0, bv1);
  }
#undef GLOADX
#undef GLOADW

  // ---- epilogue: LDS transpose for coalesced NCHW stores ----
  __syncthreads();  // all MFMA reads done before overwriting lds as S2
  float* S2 = reinterpret_cast<float*>(lds);
  int l15 = lane & 15;
#pragma unroll
  for (int m = 0; m < 8; ++m) {
#pragma unroll
    for (int i2 = 0; i2 < 4; ++i2) {
      int px = m * 16 + ((lane >> 4) * 4) + i2;
      int o = wave * 16 + l15;
      S2[px * 65 + o] = acc[m][i2];
    }
  }
  __syncthreads();
  {
    int px = t & 127, o2 = t >> 7;
    float* op = out + (((size_t)b * OO) * HH + h) * WW + px;
#pragma unroll
    for (int o4 = 0; o4 < 32; ++o4) {
      int o = o4 * 2 + o2;
      op[(size_t)o * HH * WW] = S2[px * 65 + o] + bias[o];
    }
  }
}

// ---------------------------------------------------------------------------
extern "C" void kernel_launch(void* const* d_in, const int* in_sizes, int n_in,
                              void* d_out, int out_size, void* d_ws, size_t ws_size,
                              hipStream_t stream) {
  const float* x = (const float*)d_in[0];
  const float* offset = (const float*)d_in[1];
  const float* weight = (const float*)d_in[2];
  const float* bias = (const float*)d_in[3];
  float* out = (float*)d_out;

  unsigned short* xt = (unsigned short*)d_ws;                       // 17,305,600 B
  unsigned short* wf = (unsigned short*)((char*)d_ws + 17305600);   //     73,728 B

  k_xpose<<<BB * HH, 256, 0, stream>>>(x, xt);
  k_wfrag<<<144, 256, 0, stream>>>(weight, wf);
  k_deform_main<<<BB * HH, 256, 0, stream>>>(offset, bias, xt, wf, out);
}

// Round 11
// 53.607 us; speedup vs baseline: 1.2156x; 1.0401x over previous
//
#include <hip/hip_runtime.h>
#include <hip/hip_bf16.h>

// Problem constants (from reference)
#define BB 8
#define CC 64
#define OO 64
#define HH 128
#define WW 128
#define HP 130   // padded
#define WP 130
#define KP 9

typedef __attribute__((ext_vector_type(8))) short bf16x8;
typedef __attribute__((ext_vector_type(4))) float f32x4;
typedef __attribute__((ext_vector_type(4))) unsigned u32x4;

#define ROWB 16640u   // x_t row stride in bytes = WP*CC*2

static __device__ __forceinline__ unsigned short f2bf(float f) {
  unsigned u = __float_as_uint(f);
  unsigned r = u + 0x7fffu + ((u >> 16) & 1u);
  return (unsigned short)(r >> 16);
}
static __device__ __forceinline__ f32x4 unpk4(unsigned lo, unsigned hi) {
  f32x4 r;
  r.x = __uint_as_float(lo << 16);
  r.y = __uint_as_float(lo & 0xffff0000u);
  r.z = __uint_as_float(hi << 16);
  r.w = __uint_as_float(hi & 0xffff0000u);
  return r;
}

// ---------------------------------------------------------------------------
// Kernel 1: x [B][C][H][W] f32 -> x_t [B][HP][WP][C] bf16, zero borders.
// XCD-swizzled so XCD k produces x_t[b=k] into its own L2.
// ---------------------------------------------------------------------------
__global__ __launch_bounds__(256) void k_xpose(const float* __restrict__ x,
                                               unsigned short* __restrict__ xt) {
  __shared__ unsigned short tile[128][66];
  int wg0 = blockIdx.x;           // B*H = 1024
  int wg = (wg0 & 7) * 128 + (wg0 >> 3);   // XCD-chunked: XCD k gets b=k
  int h = wg & 127, b = wg >> 7;
  int t = threadIdx.x;
  int w = t & 127, chalf = t >> 7;
  const float* xp = x + ((size_t)(b * CC) * HH + h) * WW;
#pragma unroll 4
  for (int c2 = 0; c2 < 32; ++c2) {
    int c = c2 * 2 + chalf;
    float v = xp[(size_t)c * HH * WW + w];
    tile[w][c] = f2bf(v);
  }
  __syncthreads();
  int c = t & 63, w2 = t >> 6;
  unsigned short* xtb = xt + (size_t)b * HP * WP * CC;
#pragma unroll 4
  for (int w4 = 0; w4 < 32; ++w4) {
    int ww = w4 * 4 + w2;
    xtb[((size_t)(h + 1) * WP + (ww + 1)) * CC + c] = tile[ww][c];
  }
  if (t < 128) {
    int xx = (t >= 64) ? (WP - 1) : 0;
    xtb[((size_t)(h + 1) * WP + xx) * CC + (t & 63)] = 0;
  }
  if (h == 0) {
    for (int i = t; i < 2 * WP * CC; i += 256) {
      int top = (i < WP * CC);
      int rem = top ? i : i - WP * CC;
      size_t y = top ? 0 : (HP - 1);
      xtb[y * WP * CC + rem] = 0;
    }
  }
}

// ---------------------------------------------------------------------------
// Kernel 2: weight -> bf16 MFMA B-fragments.
// byte(f, lane, j): f = (p*2+ks)*4+nf ; c = ks*32+(lane>>4)*8+j ; o = nf*16+(lane&15)
// ---------------------------------------------------------------------------
__global__ __launch_bounds__(256) void k_wfrag(const float* __restrict__ wsrc,
                                               unsigned short* __restrict__ wf) {
  int flat = blockIdx.x * 256 + threadIdx.x;
  int j = flat & 7;
  int lane = (flat >> 3) & 63;
  int nf = (flat >> 9) & 3;
  int ks = (flat >> 11) & 1;
  int p = flat >> 12;
  int c = ks * 32 + ((lane >> 4) * 8) + j;
  int o = nf * 16 + (lane & 15);
  wf[flat] = f2bf(wsrc[(size_t)(o * CC + c) * KP + p]);
}

// ---------------------------------------------------------------------------
// Main kernel. One wg = (b, h, 64-px tile) x all 64 outputs. 4 waves.
// r6's PROVEN pipeline (single e/g buffers, counted vmcnt, 1 barrier/p) at
// M=64 so live asm-load state is only g[8]=32 VGPR -> no launch_bounds cap
// needed, natural VGPR ~100 -> 4 waves/SIMD. Coords packed to 8 B/entry
// (base+flags u32, wy1/wx1 packed f16) -> LDS 20992 B -> 4 blocks/CU.
// Grid 2048 = 4/CU x 256 x 2 rounds, zero tail.
// Queue ledger per p: [g8] +wf2 -> vmcnt(2) BUILD -> bar -> ISSUE(p+1)
// -> vmcnt(8) drains wf -> MFMA.  (p=8: vmcnt(0).)
// ---------------------------------------------------------------------------
__global__ __launch_bounds__(256) void k_deform_main(const float* __restrict__ offset,
                                                     const float* __restrict__ bias,
                                                     const unsigned short* __restrict__ xt,
                                                     const unsigned short* __restrict__ wf,
                                                     float* __restrict__ out) {
  __shared__ __align__(16) char lds[20992];
  // [0,16384)      S double buffer: 2 x (64 px * 128 B, XOR-swizzled rows)
  // [16384,20992)  coords: 4 waves * 144 entries * 8 B
  // epilogue reuses [0,16640) as S2: f32 [64][65]
  int wg0 = blockIdx.x;                    // 2048
  int wgs = (wg0 & 7) * 256 + (wg0 >> 3);  // XCD k -> b=k
  int tile = wgs & 1, h = (wgs >> 1) & 127, b = wgs >> 8;
  int w0 = tile * 64;
  int t = threadIdx.x, wave = t >> 6, lane = t & 63;

  char* S0 = lds;
  uint2* cw = reinterpret_cast<uint2*>(lds + 16384) + wave * 144;

  // ---- phase 1: coordinate precompute (144 (p,pxl) pairs / wave, 8B packed) ----
  // word0 = corner00 byte offset (22b) | dxflag<<30 | dyflag<<31
  // word1 = f16(wy1) | f16(wx1)<<16
#pragma unroll
  for (int it = 0; it < 3; ++it) {
    int pair = it * 64 + lane;
    if (pair < 144) {
      int p = pair >> 4, pxl = pair & 15;
      int px = wave * 16 + pxl;
      int w = w0 + px;
      const float* offp = offset + (((size_t)b * 18 + 2 * p) * HH + h) * WW + w;
      float offy = offp[0];
      float offx = offp[HH * WW];
      float cy = (float)(h + p / 3) + offy;
      float cx = (float)(w + p % 3) + offx;
      float y0f = floorf(cy), x0f = floorf(cx);
      float wy1 = cy - y0f, wx1 = cx - x0f;
      int iy0 = (int)y0f, ix0 = (int)x0f;
      int iy0c = min(max(iy0, 0), HP - 1);
      int iy1c = min(max(iy0 + 1, 0), HP - 1);
      int ix0c = min(max(ix0, 0), WP - 1);
      int ix1c = min(max(ix0 + 1, 0), WP - 1);
      unsigned w0p = (unsigned)((iy0c * WP + ix0c) * (CC * 2));
      if (ix1c != ix0c) w0p |= (1u << 30);
      if (iy1c != iy0c) w0p |= (1u << 31);
      unsigned hv;
      asm("v_cvt_pkrtz_f16_f32 %0, %1, %2" : "=v"(hv) : "v"(wy1), "v"(wx1));
      uint2 ce;
      ce.x = w0p;
      ce.y = hv;
      cw[pair] = ce;
    }
  }

  f32x4 acc[4];
#pragma unroll
  for (int m = 0; m < 4; ++m) acc[m] = (f32x4){0.f, 0.f, 0.f, 0.f};

  const char* xb = (const char*)(xt + (size_t)b * HP * WP * CC);
  int c8 = lane & 7, pg = lane >> 3;
  unsigned cb = (unsigned)c8 * 16;              // byte offset of this lane's 8 channels
  unsigned swz = cb ^ ((unsigned)pg << 4);      // write column (XOR row swizzle)
  const uint2* cwl = cw + pg;                   // + p*16 + it*8

#define GLOADX(dst, voff) \
  asm volatile("global_load_dwordx4 %0, %1, %2" \
               : "=v"(dst) : "v"(voff), "s"(xb) : "memory")
#define GLOADW(dst, voff) \
  asm volatile("global_load_dwordx4 %0, %1, %2" \
               : "=v"(dst) : "v"(voff), "s"(wf) : "memory")

  auto LOADC = [&](int p, uint2* eo) {
#pragma unroll
    for (int it = 0; it < 2; ++it) eo[it] = cwl[p * 16 + it * 8];
  };
  auto ISSUE = [&](const uint2* ei, u32x4* go) {
#pragma unroll
    for (int it = 0; it < 2; ++it) {
      unsigned w0p = ei[it].x;
      unsigned a00 = (w0p & 0x003FFFFFu) + cb;
      unsigned dx = ((w0p >> 30) & 1u) << 7;                  // 0 or 128 B (CC*2)
      unsigned dy = (w0p & 0x80000000u) ? ROWB : 0u;          // 0 or WP*CC*2 = 16640
      unsigned a01 = a00 + dx, a10 = a00 + dy, a11 = a10 + dx;
      GLOADX(go[it * 4 + 0], a00);
      GLOADX(go[it * 4 + 1], a01);
      GLOADX(go[it * 4 + 2], a10);
      GLOADX(go[it * 4 + 3], a11);
    }
  };
  auto BUILD = [&](const uint2* ei, const u32x4* gi, char* Sc) {
    char* swave = Sc + wave * 2048 + pg * 128;
#pragma unroll
    for (int it = 0; it < 2; ++it) {
      unsigned w1p = ei[it].y, w1hi = w1p >> 16;
      float wy1, wx1;
      asm("v_cvt_f32_f16 %0, %1" : "=v"(wy1) : "v"(w1p));
      asm("v_cvt_f32_f16 %0, %1" : "=v"(wx1) : "v"(w1hi));
      u32x4 q00 = gi[it * 4 + 0], q01 = gi[it * 4 + 1];
      u32x4 q10 = gi[it * 4 + 2], q11 = gi[it * 4 + 3];
      f32x4 a00 = unpk4(q00.x, q00.y), a01 = unpk4(q01.x, q01.y);
      f32x4 a10 = unpk4(q10.x, q10.y), a11 = unpk4(q11.x, q11.y);
      f32x4 topA = a00 + wx1 * (a01 - a00);
      f32x4 botA = a10 + wx1 * (a11 - a10);
      f32x4 sA = topA + wy1 * (botA - topA);
      f32x4 b00 = unpk4(q00.z, q00.w), b01 = unpk4(q01.z, q01.w);
      f32x4 b10 = unpk4(q10.z, q10.w), b11 = unpk4(q11.z, q11.w);
      f32x4 topB = b00 + wx1 * (b01 - b00);
      f32x4 botB = b10 + wx1 * (b11 - b10);
      f32x4 sB = topB + wy1 * (botB - topB);
      unsigned r0, r1, r2, r3;
      asm("v_cvt_pk_bf16_f32 %0, %1, %2" : "=v"(r0) : "v"(sA.x), "v"(sA.y));
      asm("v_cvt_pk_bf16_f32 %0, %1, %2" : "=v"(r1) : "v"(sA.z), "v"(sA.w));
      asm("v_cvt_pk_bf16_f32 %0, %1, %2" : "=v"(r2) : "v"(sB.x), "v"(sB.y));
      asm("v_cvt_pk_bf16_f32 %0, %1, %2" : "=v"(r3) : "v"(sB.z), "v"(sB.w));
      u32x4 pk; pk.x = r0; pk.y = r1; pk.z = r2; pk.w = r3;
      *reinterpret_cast<u32x4*>(swave + it * 1024 + swz) = pk;
    }
  };
  auto MFMA = [&](const char* Sc, bf16x8 b0, bf16x8 b1) {
    int l15 = lane & 15, kc = (lane >> 4) * 16, sw = (lane & 7) << 4;
#pragma unroll
    for (int m = 0; m < 4; ++m) {
      int rb = (m * 16 + l15) * 128;
      bf16x8 a0 = *reinterpret_cast<const bf16x8*>(Sc + rb + (kc ^ sw));
      bf16x8 a1 = *reinterpret_cast<const bf16x8*>(Sc + rb + ((64 + kc) ^ sw));
      acc[m] = __builtin_amdgcn_mfma_f32_16x16x32_bf16(a0, b0, acc[m], 0, 0, 0);
      acc[m] = __builtin_amdgcn_mfma_f32_16x16x32_bf16(a1, b1, acc[m], 0, 0, 0);
    }
  };

  // ---- pipelined p-loop (r6-proven ledger) ----
  uint2 e[2];
  u32x4 g[8];
  LOADC(0, e);
  ISSUE(e, g);                     // queue [g8]
#pragma unroll
  for (int p = 0; p < 9; ++p) {
    char* Sc = S0 + (p & 1) * 8192;
    bf16x8 bv0, bv1;
    unsigned wfo = (unsigned)((p * 8 + wave) * 1024 + lane * 16);
    GLOADW(bv0, wfo);
    GLOADW(bv1, wfo + 4096);       // queue [g8, wf2] = 10
    asm volatile("s_waitcnt vmcnt(2)" ::: "memory");   // drain g; wf flying
    __builtin_amdgcn_sched_barrier(0);
    BUILD(e, g, Sc);               // consumes g, writes own S slice
    if (p < 8) LOADC(p + 1, e);    // e dead after BUILD — reuse
    // S + coords visible; all waves' MFMA(p-1) LDS reads drained
    asm volatile("s_waitcnt lgkmcnt(0)" ::: "memory");
    __builtin_amdgcn_s_barrier();
    if (p < 8) {
      ISSUE(e, g);                 // queue [wf2, g8] = 10
      asm volatile("s_waitcnt vmcnt(8)" ::: "memory"); // drain wf
    } else {
      asm volatile("s_waitcnt vmcnt(0)" ::: "memory");
    }
    __builtin_amdgcn_sched_barrier(0);
    MFMA(Sc, bv0, bv1);
  }
#undef GLOADX
#undef GLOADW

  // ---- epilogue: LDS transpose for coalesced NCHW stores ----
  __syncthreads();  // all MFMA reads done before overwriting lds as S2
  float* S2 = reinterpret_cast<float*>(lds);
  int l15 = lane & 15;
#pragma unroll
  for (int m = 0; m < 4; ++m) {
#pragma unroll
    for (int i2 = 0; i2 < 4; ++i2) {
      int px = m * 16 + ((lane >> 4) * 4) + i2;
      int o = wave * 16 + l15;
      S2[px * 65 + o] = acc[m][i2];
    }
  }
  __syncthreads();
  {
    int px = t & 63, o2 = t >> 6;
    float* op = out + (((size_t)b * OO) * HH + h) * WW + w0 + px;
#pragma unroll
    for (int o4 = 0; o4 < 16; ++o4) {
      int o = o4 * 4 + o2;
      op[(size_t)o * HH * WW] = S2[px * 65 + o] + bias[o];
    }
  }
}

// ---------------------------------------------------------------------------
extern "C" void kernel_launch(void* const* d_in, const int* in_sizes, int n_in,
                              void* d_out, int out_size, void* d_ws, size_t ws_size,
                              hipStream_t stream) {
  const float* x = (const float*)d_in[0];
  const float* offset = (const float*)d_in[1];
  const float* weight = (const float*)d_in[2];
  const float* bias = (const float*)d_in[3];
  float* out = (float*)d_out;

  unsigned short* xt = (unsigned short*)d_ws;                       // 17,305,600 B
  unsigned short* wf = (unsigned short*)((char*)d_ws + 17305600);   //     73,728 B

  k_xpose<<<BB * HH, 256, 0, stream>>>(x, xt);
  k_wfrag<<<144, 256, 0, stream>>>(weight, wf);
  k_deform_main<<<BB * HH * 2, 256, 0, stream>>>(offset, bias, xt, wf, out);
}

// Round 12
// 53.477 us; speedup vs baseline: 1.2186x; 1.0024x over previous
//
#include <hip/hip_runtime.h>
#include <hip/hip_bf16.h>

// Problem constants (from reference)
#define BB 8
#define CC 64
#define OO 64
#define HH 128
#define WW 128
#define HP 130   // padded
#define WP 130
#define KP 9

typedef __attribute__((ext_vector_type(8))) short bf16x8;
typedef __attribute__((ext_vector_type(4))) float f32x4;
typedef __attribute__((ext_vector_type(4))) unsigned u32x4;

#define ROWB 16640u   // x_t row stride in bytes = WP*CC*2

static __device__ __forceinline__ unsigned short f2bf(float f) {
  unsigned u = __float_as_uint(f);
  unsigned r = u + 0x7fffu + ((u >> 16) & 1u);
  return (unsigned short)(r >> 16);
}
static __device__ __forceinline__ f32x4 unpk4(unsigned lo, unsigned hi) {
  f32x4 r;
  r.x = __uint_as_float(lo << 16);
  r.y = __uint_as_float(lo & 0xffff0000u);
  r.z = __uint_as_float(hi << 16);
  r.w = __uint_as_float(hi & 0xffff0000u);
  return r;
}

// ---------------------------------------------------------------------------
// Kernel 1: x [B][C][H][W] f32 -> x_t [B][HP][WP][C] bf16, zero borders.
// XCD-swizzled so XCD k produces x_t[b=k] into its own L2.
// ---------------------------------------------------------------------------
__global__ __launch_bounds__(256) void k_xpose(const float* __restrict__ x,
                                               unsigned short* __restrict__ xt) {
  __shared__ unsigned short tile[128][66];
  int wg0 = blockIdx.x;           // B*H = 1024
  int wg = (wg0 & 7) * 128 + (wg0 >> 3);   // XCD-chunked: XCD k gets b=k
  int h = wg & 127, b = wg >> 7;
  int t = threadIdx.x;
  int w = t & 127, chalf = t >> 7;
  const float* xp = x + ((size_t)(b * CC) * HH + h) * WW;
#pragma unroll 4
  for (int c2 = 0; c2 < 32; ++c2) {
    int c = c2 * 2 + chalf;
    float v = xp[(size_t)c * HH * WW + w];
    tile[w][c] = f2bf(v);
  }
  __syncthreads();
  int c = t & 63, w2 = t >> 6;
  unsigned short* xtb = xt + (size_t)b * HP * WP * CC;
#pragma unroll 4
  for (int w4 = 0; w4 < 32; ++w4) {
    int ww = w4 * 4 + w2;
    xtb[((size_t)(h + 1) * WP + (ww + 1)) * CC + c] = tile[ww][c];
  }
  if (t < 128) {
    int xx = (t >= 64) ? (WP - 1) : 0;
    xtb[((size_t)(h + 1) * WP + xx) * CC + (t & 63)] = 0;
  }
  if (h == 0) {
    for (int i = t; i < 2 * WP * CC; i += 256) {
      int top = (i < WP * CC);
      int rem = top ? i : i - WP * CC;
      size_t y = top ? 0 : (HP - 1);
      xtb[y * WP * CC + rem] = 0;
    }
  }
}

// ---------------------------------------------------------------------------
// Kernel 2: weight -> bf16 MFMA B-fragments.
// byte(f, lane, j): f = (p*2+ks)*4+nf ; c = ks*32+(lane>>4)*8+j ; o = nf*16+(lane&15)
// ---------------------------------------------------------------------------
__global__ __launch_bounds__(256) void k_wfrag(const float* __restrict__ wsrc,
                                               unsigned short* __restrict__ wf) {
  int flat = blockIdx.x * 256 + threadIdx.x;
  int j = flat & 7;
  int lane = (flat >> 3) & 63;
  int nf = (flat >> 9) & 3;
  int ks = (flat >> 11) & 1;
  int p = flat >> 12;
  int c = ks * 32 + ((lane >> 4) * 8) + j;
  int o = nf * 16 + (lane & 15);
  wf[flat] = f2bf(wsrc[(size_t)(o * CC + c) * KP + p]);
}

// ---------------------------------------------------------------------------
// Main kernel. One wg = (b, h, 64-px tile) x all 64 outputs. 4 waves.
// 2-deep gather pipeline + 1-deep weight prefetch, all hand-counted vmcnt.
// Steady ledger entering p: [g(p)8, wf(p)2, g(p+1)8] = 18.
//   vmcnt(10) -> BUILD(p) -> LOADC(p+2) -> lgkm(0)+bar ->
//   wf(p+1)x2, g(p+2)x8 -> vmcnt(18) drains wf(p) -> MFMA(p).
// Tails: p=7 step7 vmcnt(10); p=8 step1 vmcnt(2), step7 vmcnt(0).
// Ping-pong e/g/bv by parity (p compile-time -> static indexing).
// NO launch_bounds: allocator must never spill asm-load dsts (r7/r8 lesson).
// ---------------------------------------------------------------------------
__global__ __launch_bounds__(256) void k_deform_main(const float* __restrict__ offset,
                                                     const float* __restrict__ bias,
                                                     const unsigned short* __restrict__ xt,
                                                     const unsigned short* __restrict__ wf,
                                                     float* __restrict__ out) {
  __shared__ __align__(16) char lds[20992];
  // [0,16384)      S double buffer: 2 x (64 px * 128 B, XOR-swizzled rows)
  // [16384,20992)  coords: 4 waves * 144 entries * 8 B
  // epilogue reuses [0,16640) as S2: f32 [64][65]
  int wg0 = blockIdx.x;                    // 2048
  int wgs = (wg0 & 7) * 256 + (wg0 >> 3);  // XCD k -> b=k
  int tile = wgs & 1, h = (wgs >> 1) & 127, b = wgs >> 8;
  int w0 = tile * 64;
  int t = threadIdx.x, wave = t >> 6, lane = t & 63;

  char* S0 = lds;
  uint2* cw = reinterpret_cast<uint2*>(lds + 16384) + wave * 144;

  // ---- phase 1: coordinate precompute (144 (p,pxl) pairs / wave, 8B packed) ----
  // word0 = corner00 byte offset (22b) | dxflag<<30 | dyflag<<31
  // word1 = f16(wy1) | f16(wx1)<<16
#pragma unroll
  for (int it = 0; it < 3; ++it) {
    int pair = it * 64 + lane;
    if (pair < 144) {
      int p = pair >> 4, pxl = pair & 15;
      int px = wave * 16 + pxl;
      int w = w0 + px;
      const float* offp = offset + (((size_t)b * 18 + 2 * p) * HH + h) * WW + w;
      float offy = offp[0];
      float offx = offp[HH * WW];
      float cy = (float)(h + p / 3) + offy;
      float cx = (float)(w + p % 3) + offx;
      float y0f = floorf(cy), x0f = floorf(cx);
      float wy1 = cy - y0f, wx1 = cx - x0f;
      int iy0 = (int)y0f, ix0 = (int)x0f;
      int iy0c = min(max(iy0, 0), HP - 1);
      int iy1c = min(max(iy0 + 1, 0), HP - 1);
      int ix0c = min(max(ix0, 0), WP - 1);
      int ix1c = min(max(ix0 + 1, 0), WP - 1);
      unsigned w0p = (unsigned)((iy0c * WP + ix0c) * (CC * 2));
      if (ix1c != ix0c) w0p |= (1u << 30);
      if (iy1c != iy0c) w0p |= (1u << 31);
      unsigned hv;
      asm("v_cvt_pkrtz_f16_f32 %0, %1, %2" : "=v"(hv) : "v"(wy1), "v"(wx1));
      uint2 ce;
      ce.x = w0p;
      ce.y = hv;
      cw[pair] = ce;
    }
  }

  f32x4 acc[4];
#pragma unroll
  for (int m = 0; m < 4; ++m) acc[m] = (f32x4){0.f, 0.f, 0.f, 0.f};

  const char* xb = (const char*)(xt + (size_t)b * HP * WP * CC);
  int c8 = lane & 7, pg = lane >> 3;
  unsigned cb = (unsigned)c8 * 16;              // byte offset of this lane's 8 channels
  unsigned swz = cb ^ ((unsigned)pg << 4);      // write column (XOR row swizzle)
  const uint2* cwl = cw + pg;                   // + p*16 + it*8

#define GLOADX(dst, voff) \
  asm volatile("global_load_dwordx4 %0, %1, %2" \
               : "=v"(dst) : "v"(voff), "s"(xb) : "memory")
#define GLOADW(dst, voff) \
  asm volatile("global_load_dwordx4 %0, %1, %2" \
               : "=v"(dst) : "v"(voff), "s"(wf) : "memory")

  auto LOADC = [&](int p, uint2* eo) {
#pragma unroll
    for (int it = 0; it < 2; ++it) eo[it] = cwl[p * 16 + it * 8];
  };
  auto ISSUE = [&](const uint2* ei, u32x4* go) {
#pragma unroll
    for (int it = 0; it < 2; ++it) {
      unsigned w0p = ei[it].x;
      unsigned a00 = (w0p & 0x003FFFFFu) + cb;
      unsigned dx = ((w0p >> 30) & 1u) << 7;                  // 0 or 128 B (CC*2)
      unsigned dy = (w0p & 0x80000000u) ? ROWB : 0u;          // 0 or 16640
      unsigned a01 = a00 + dx, a10 = a00 + dy, a11 = a10 + dx;
      GLOADX(go[it * 4 + 0], a00);
      GLOADX(go[it * 4 + 1], a01);
      GLOADX(go[it * 4 + 2], a10);
      GLOADX(go[it * 4 + 3], a11);
    }
  };
  auto BUILD = [&](const uint2* ei, const u32x4* gi, char* Sc) {
    char* swave = Sc + wave * 2048 + pg * 128;
#pragma unroll
    for (int it = 0; it < 2; ++it) {
      unsigned w1p = ei[it].y, w1hi = w1p >> 16;
      float wy1, wx1;
      asm("v_cvt_f32_f16 %0, %1" : "=v"(wy1) : "v"(w1p));
      asm("v_cvt_f32_f16 %0, %1" : "=v"(wx1) : "v"(w1hi));
      // corner weights: mul + 3 fma per channel instead of 3 lerps
      float w11 = wy1 * wx1;
      float w01 = wx1 - w11;          // wx1*(1-wy1)
      float w10 = wy1 - w11;          // wy1*(1-wx1)
      float w00 = 1.0f - wx1 - w10;   // (1-wx1)*(1-wy1)
      u32x4 q00 = gi[it * 4 + 0], q01 = gi[it * 4 + 1];
      u32x4 q10 = gi[it * 4 + 2], q11 = gi[it * 4 + 3];
      f32x4 a00 = unpk4(q00.x, q00.y), a01 = unpk4(q01.x, q01.y);
      f32x4 a10 = unpk4(q10.x, q10.y), a11 = unpk4(q11.x, q11.y);
      f32x4 sA = w00 * a00 + w01 * a01 + w10 * a10 + w11 * a11;
      f32x4 b00 = unpk4(q00.z, q00.w), b01 = unpk4(q01.z, q01.w);
      f32x4 b10 = unpk4(q10.z, q10.w), b11 = unpk4(q11.z, q11.w);
      f32x4 sB = w00 * b00 + w01 * b01 + w10 * b10 + w11 * b11;
      unsigned r0, r1, r2, r3;
      asm("v_cvt_pk_bf16_f32 %0, %1, %2" : "=v"(r0) : "v"(sA.x), "v"(sA.y));
      asm("v_cvt_pk_bf16_f32 %0, %1, %2" : "=v"(r1) : "v"(sA.z), "v"(sA.w));
      asm("v_cvt_pk_bf16_f32 %0, %1, %2" : "=v"(r2) : "v"(sB.x), "v"(sB.y));
      asm("v_cvt_pk_bf16_f32 %0, %1, %2" : "=v"(r3) : "v"(sB.z), "v"(sB.w));
      u32x4 pk; pk.x = r0; pk.y = r1; pk.z = r2; pk.w = r3;
      *reinterpret_cast<u32x4*>(swave + it * 1024 + swz) = pk;
    }
  };
  auto MFMA = [&](const char* Sc, bf16x8 b0, bf16x8 b1) {
    int l15 = lane & 15, kc = (lane >> 4) * 16, sw = (lane & 7) << 4;
#pragma unroll
    for (int m = 0; m < 4; ++m) {
      int rb = (m * 16 + l15) * 128;
      bf16x8 a0 = *reinterpret_cast<const bf16x8*>(Sc + rb + (kc ^ sw));
      bf16x8 a1 = *reinterpret_cast<const bf16x8*>(Sc + rb + ((64 + kc) ^ sw));
      acc[m] = __builtin_amdgcn_mfma_f32_16x16x32_bf16(a0, b0, acc[m], 0, 0, 0);
      acc[m] = __builtin_amdgcn_mfma_f32_16x16x32_bf16(a1, b1, acc[m], 0, 0, 0);
    }
  };

  // ---- prologue: prime queue [g0(8), wf0(2), g1(8)] ----
  uint2 eA[2], eB[2];
  u32x4 gA[8], gB[8];
  bf16x8 bvA0, bvA1, bvB0, bvB1;
  LOADC(0, eA);
  ISSUE(eA, gA);                       // g0 x8
  {
    unsigned wfo = (unsigned)((0 * 8 + wave) * 1024 + lane * 16);
    GLOADW(bvA0, wfo);                 // wf0 x2
    GLOADW(bvA1, wfo + 4096);
  }
  LOADC(1, eB);
  ISSUE(eB, gB);                       // g1 x8

  // ---- 2-deep pipelined p-loop ----
#pragma unroll
  for (int p = 0; p < 9; ++p) {
    char* Sc = S0 + (p & 1) * 8192;
    uint2* eCur = (p & 1) ? eB : eA;
    u32x4* gCur = (p & 1) ? gB : gA;
    // step 1: drain g(p)  (queue [g(p)8, wf(p)2, g(p+1)8] -> keep 10)
    if (p < 8) {
      asm volatile("s_waitcnt vmcnt(10)" ::: "memory");
    } else {
      asm volatile("s_waitcnt vmcnt(2)" ::: "memory");
    }
    __builtin_amdgcn_sched_barrier(0);
    // step 2: bilinear + S write
    BUILD(eCur, gCur, Sc);
    // step 3: coords for p+2 (LDS read into freed e regs)
    if (p < 7) LOADC(p + 2, eCur);
    // step 4: S + coords visible; all waves' MFMA(p-1) LDS reads drained
    asm volatile("s_waitcnt lgkmcnt(0)" ::: "memory");
    __builtin_amdgcn_s_barrier();
    // step 5: weight fragments for p+1 (into opposite-parity bv)
    if (p < 8) {
      unsigned wfo = (unsigned)(((p + 1) * 8 + wave) * 1024 + lane * 16);
      if (p & 1) { GLOADW(bvA0, wfo); GLOADW(bvA1, wfo + 4096); }
      else       { GLOADW(bvB0, wfo); GLOADW(bvB1, wfo + 4096); }
    }
    // step 6: gathers for p+2 (into freed g regs)
    if (p < 7) ISSUE(eCur, gCur);
    // step 7: drain wf(p); keep g(p+1), wf(p+1), g(p+2) in flight
    if (p < 7) {
      asm volatile("s_waitcnt vmcnt(18)" ::: "memory");
    } else if (p == 7) {
      asm volatile("s_waitcnt vmcnt(10)" ::: "memory");
    } else {
      asm volatile("s_waitcnt vmcnt(0)" ::: "memory");
    }
    __builtin_amdgcn_sched_barrier(0);
    // step 8: MFMA with this p's weights
    if (p & 1) MFMA(Sc, bvB0, bvB1);
    else       MFMA(Sc, bvA0, bvA1);
  }
#undef GLOADX
#undef GLOADW

  // ---- epilogue: LDS transpose for coalesced NCHW stores ----
  __syncthreads();  // all MFMA reads done before overwriting lds as S2
  float* S2 = reinterpret_cast<float*>(lds);
  int l15 = lane & 15;
#pragma unroll
  for (int m = 0; m < 4; ++m) {
#pragma unroll
    for (int i2 = 0; i2 < 4; ++i2) {
      int px = m * 16 + ((lane >> 4) * 4) + i2;
      int o = wave * 16 + l15;
      S2[px * 65 + o] = acc[m][i2];
    }
  }
  __syncthreads();
  {
    int px = t & 63, o2 = t >> 6;
    float* op = out + (((size_t)b * OO) * HH + h) * WW + w0 + px;
#pragma unroll
    for (int o4 = 0; o4 < 16; ++o4) {
      int o = o4 * 4 + o2;
      op[(size_t)o * HH * WW] = S2[px * 65 + o] + bias[o];
    }
  }
}

// ---------------------------------------------------------------------------
extern "C" void kernel_launch(void* const* d_in, const int* in_sizes, int n_in,
                              void* d_out, int out_size, void* d_ws, size_t ws_size,
                              hipStream_t stream) {
  const float* x = (const float*)d_in[0];
  const float* offset = (const float*)d_in[1];
  const float* weight = (const float*)d_in[2];
  const float* bias = (const float*)d_in[3];
  float* out = (float*)d_out;

  unsigned short* xt = (unsigned short*)d_ws;                       // 17,305,600 B
  unsigned short* wf = (unsigned short*)((char*)d_ws + 17305600);   //     73,728 B

  k_xpose<<<BB * HH, 256, 0, stream>>>(x, xt);
  k_wfrag<<<144, 256, 0, stream>>>(weight, wf);
  k_deform_main<<<BB * HH * 2, 256, 0, stream>>>(offset, bias, xt, wf, out);
}

// Round 13
// 48.515 us; speedup vs baseline: 1.3432x; 1.1023x over previous
//
#include <hip/hip_runtime.h>
#include <hip/hip_bf16.h>

// Problem constants (from reference)
#define BB 8
#define CC 64
#define OO 64
#define HH 128
#define WW 128
#define HP 130   // padded
#define WP 130
#define KP 9

typedef __attribute__((ext_vector_type(8))) _Float16 f16x8;
typedef __attribute__((ext_vector_type(2))) _Float16 h2;
typedef __attribute__((ext_vector_type(4))) float f32x4;
typedef __attribute__((ext_vector_type(4))) unsigned u32x4;

#define ROWB 16640u   // x_t row stride in bytes = WP*CC*2

static __device__ __forceinline__ unsigned short f2h(float f) {
  _Float16 h = (_Float16)f;
  return __builtin_bit_cast(unsigned short, h);
}
static __device__ __forceinline__ h2 asH2(unsigned u) {
  return __builtin_bit_cast(h2, u);
}
static __device__ __forceinline__ unsigned asU32(h2 v) {
  return __builtin_bit_cast(unsigned, v);
}

// ---------------------------------------------------------------------------
// Kernel 1: x [B][C][H][W] f32 -> x_t [B][HP][WP][C] f16, zero borders.
// XCD-swizzled so XCD k produces x_t[b=k] into its own L2.
// ---------------------------------------------------------------------------
__global__ __launch_bounds__(256) void k_xpose(const float* __restrict__ x,
                                               unsigned short* __restrict__ xt) {
  __shared__ unsigned short tile[128][66];
  int wg0 = blockIdx.x;           // B*H = 1024
  int wg = (wg0 & 7) * 128 + (wg0 >> 3);   // XCD-chunked: XCD k gets b=k
  int h = wg & 127, b = wg >> 7;
  int t = threadIdx.x;
  int w = t & 127, chalf = t >> 7;
  const float* xp = x + ((size_t)(b * CC) * HH + h) * WW;
#pragma unroll 4
  for (int c2 = 0; c2 < 32; ++c2) {
    int c = c2 * 2 + chalf;
    float v = xp[(size_t)c * HH * WW + w];
    tile[w][c] = f2h(v);
  }
  __syncthreads();
  int c = t & 63, w2 = t >> 6;
  unsigned short* xtb = xt + (size_t)b * HP * WP * CC;
#pragma unroll 4
  for (int w4 = 0; w4 < 32; ++w4) {
    int ww = w4 * 4 + w2;
    xtb[((size_t)(h + 1) * WP + (ww + 1)) * CC + c] = tile[ww][c];
  }
  if (t < 128) {
    int xx = (t >= 64) ? (WP - 1) : 0;
    xtb[((size_t)(h + 1) * WP + xx) * CC + (t & 63)] = 0;
  }
  if (h == 0) {
    for (int i = t; i < 2 * WP * CC; i += 256) {
      int top = (i < WP * CC);
      int rem = top ? i : i - WP * CC;
      size_t y = top ? 0 : (HP - 1);
      xtb[y * WP * CC + rem] = 0;
    }
  }
}

// ---------------------------------------------------------------------------
// Kernel 2: weight -> f16 MFMA B-fragments.
// byte(f, lane, j): f = (p*2+ks)*4+nf ; c = ks*32+(lane>>4)*8+j ; o = nf*16+(lane&15)
// ---------------------------------------------------------------------------
__global__ __launch_bounds__(256) void k_wfrag(const float* __restrict__ wsrc,
                                               unsigned short* __restrict__ wf) {
  int flat = blockIdx.x * 256 + threadIdx.x;
  int j = flat & 7;
  int lane = (flat >> 3) & 63;
  int nf = (flat >> 9) & 3;
  int ks = (flat >> 11) & 1;
  int p = flat >> 12;
  int c = ks * 32 + ((lane >> 4) * 8) + j;
  int o = nf * 16 + (lane & 15);
  wf[flat] = f2h(wsrc[(size_t)(o * CC + c) * KP + p]);
}

// ---------------------------------------------------------------------------
// Main kernel. One wg = (b, h, 64-px tile) x all 64 outputs. 4 waves.
// r11's PROVEN 1-deep ledger, but the whole sampling path is f16:
// gathered u32s ARE packed f16 pairs (no unpack), bilinear = v_pk_fma_f16
// corner-weight form (16 pk ops/it for 8 channels vs 64 scalar f32 ops),
// result stored packed (no cvt_pk), MFMA = mfma_f32_16x16x32_f16.
// Queue ledger per p: [g8] +wf2 -> vmcnt(2) BUILD -> bar -> ISSUE(p+1)
// -> vmcnt(8) drains wf -> MFMA.  (p=8: vmcnt(0).)
// NO launch_bounds: allocator must never spill asm-load dsts (r7/r8 lesson).
// ---------------------------------------------------------------------------
__global__ __launch_bounds__(256) void k_deform_main(const float* __restrict__ offset,
                                                     const float* __restrict__ bias,
                                                     const unsigned short* __restrict__ xt,
                                                     const unsigned short* __restrict__ wf,
                                                     float* __restrict__ out) {
  __shared__ __align__(16) char lds[20992];
  // [0,16384)      S double buffer: 2 x (64 px * 128 B, XOR-swizzled rows)
  // [16384,20992)  coords: 4 waves * 144 entries * 8 B
  // epilogue reuses [0,16640) as S2: f32 [64][65]
  int wg0 = blockIdx.x;                    // 2048
  int wgs = (wg0 & 7) * 256 + (wg0 >> 3);  // XCD k -> b=k
  int tile = wgs & 1, h = (wgs >> 1) & 127, b = wgs >> 8;
  int w0 = tile * 64;
  int t = threadIdx.x, wave = t >> 6, lane = t & 63;

  char* S0 = lds;
  uint2* cw = reinterpret_cast<uint2*>(lds + 16384) + wave * 144;

  // ---- phase 1: coordinate precompute (144 (p,pxl) pairs / wave, 8B packed) ----
  // word0 = corner00 byte offset (22b) | dxflag<<30 | dyflag<<31
  // word1 = f16(wy1) | f16(wx1)<<16   (consumed directly as packed f16)
#pragma unroll
  for (int it = 0; it < 3; ++it) {
    int pair = it * 64 + lane;
    if (pair < 144) {
      int p = pair >> 4, pxl = pair & 15;
      int px = wave * 16 + pxl;
      int w = w0 + px;
      const float* offp = offset + (((size_t)b * 18 + 2 * p) * HH + h) * WW + w;
      float offy = offp[0];
      float offx = offp[HH * WW];
      float cy = (float)(h + p / 3) + offy;
      float cx = (float)(w + p % 3) + offx;
      float y0f = floorf(cy), x0f = floorf(cx);
      float wy1 = cy - y0f, wx1 = cx - x0f;
      int iy0 = (int)y0f, ix0 = (int)x0f;
      int iy0c = min(max(iy0, 0), HP - 1);
      int iy1c = min(max(iy0 + 1, 0), HP - 1);
      int ix0c = min(max(ix0, 0), WP - 1);
      int ix1c = min(max(ix0 + 1, 0), WP - 1);
      unsigned w0p = (unsigned)((iy0c * WP + ix0c) * (CC * 2));
      if (ix1c != ix0c) w0p |= (1u << 30);
      if (iy1c != iy0c) w0p |= (1u << 31);
      unsigned hv;
      asm("v_cvt_pkrtz_f16_f32 %0, %1, %2" : "=v"(hv) : "v"(wy1), "v"(wx1));
      uint2 ce;
      ce.x = w0p;
      ce.y = hv;
      cw[pair] = ce;
    }
  }

  f32x4 acc[4];
#pragma unroll
  for (int m = 0; m < 4; ++m) acc[m] = (f32x4){0.f, 0.f, 0.f, 0.f};

  const char* xb = (const char*)(xt + (size_t)b * HP * WP * CC);
  int c8 = lane & 7, pg = lane >> 3;
  unsigned cb = (unsigned)c8 * 16;              // byte offset of this lane's 8 channels
  unsigned swz = cb ^ ((unsigned)pg << 4);      // write column (XOR row swizzle)
  const uint2* cwl = cw + pg;                   // + p*16 + it*8

#define GLOADX(dst, voff) \
  asm volatile("global_load_dwordx4 %0, %1, %2" \
               : "=v"(dst) : "v"(voff), "s"(xb) : "memory")
#define GLOADW(dst, voff) \
  asm volatile("global_load_dwordx4 %0, %1, %2" \
               : "=v"(dst) : "v"(voff), "s"(wf) : "memory")

  auto LOADC = [&](int p, uint2* eo) {
#pragma unroll
    for (int it = 0; it < 2; ++it) eo[it] = cwl[p * 16 + it * 8];
  };
  auto ISSUE = [&](const uint2* ei, u32x4* go) {
#pragma unroll
    for (int it = 0; it < 2; ++it) {
      unsigned w0p = ei[it].x;
      unsigned a00 = (w0p & 0x003FFFFFu) + cb;
      unsigned dx = ((w0p >> 30) & 1u) << 7;                  // 0 or 128 B (CC*2)
      unsigned dy = (w0p & 0x80000000u) ? ROWB : 0u;          // 0 or 16640
      unsigned a01 = a00 + dx, a10 = a00 + dy, a11 = a10 + dx;
      GLOADX(go[it * 4 + 0], a00);
      GLOADX(go[it * 4 + 1], a01);
      GLOADX(go[it * 4 + 2], a10);
      GLOADX(go[it * 4 + 3], a11);
    }
  };
  auto BUILD = [&](const uint2* ei, const u32x4* gi, char* Sc) {
    char* swave = Sc + wave * 2048 + pg * 128;
#pragma unroll
    for (int it = 0; it < 2; ++it) {
      h2 wyx = asH2(ei[it].y);                 // {wy1, wx1} as f16
      _Float16 wy = wyx.x, wx = wyx.y;
      _Float16 w11 = wy * wx;
      _Float16 w01 = wx - w11;                 // wx*(1-wy)
      _Float16 w10 = wy - w11;                 // wy*(1-wx)
      _Float16 w00 = (_Float16)1.0f - wx - w10;
      h2 W00 = {w00, w00}, W01 = {w01, w01}, W10 = {w10, w10}, W11 = {w11, w11};
      u32x4 q00 = gi[it * 4 + 0], q01 = gi[it * 4 + 1];
      u32x4 q10 = gi[it * 4 + 2], q11 = gi[it * 4 + 3];
      u32x4 pk;
#pragma unroll
      for (int k = 0; k < 4; ++k) {
        h2 s = W00 * asH2(q00[k]) + W01 * asH2(q01[k])
             + W10 * asH2(q10[k]) + W11 * asH2(q11[k]);   // v_pk_mul + 3 v_pk_fma
        pk[k] = asU32(s);
      }
      *reinterpret_cast<u32x4*>(swave + it * 1024 + swz) = pk;
    }
  };
  auto MFMA = [&](const char* Sc, f16x8 b0, f16x8 b1) {
    int l15 = lane & 15, kc = (lane >> 4) * 16, sw = (lane & 7) << 4;
#pragma unroll
    for (int m = 0; m < 4; ++m) {
      int rb = (m * 16 + l15) * 128;
      f16x8 a0 = *reinterpret_cast<const f16x8*>(Sc + rb + (kc ^ sw));
      f16x8 a1 = *reinterpret_cast<const f16x8*>(Sc + rb + ((64 + kc) ^ sw));
      acc[m] = __builtin_amdgcn_mfma_f32_16x16x32_f16(a0, b0, acc[m], 0, 0, 0);
      acc[m] = __builtin_amdgcn_mfma_f32_16x16x32_f16(a1, b1, acc[m], 0, 0, 0);
    }
  };

  // ---- pipelined p-loop (r11-proven ledger) ----
  uint2 e[2];
  u32x4 g[8];
  LOADC(0, e);
  ISSUE(e, g);                     // queue [g8]
#pragma unroll
  for (int p = 0; p < 9; ++p) {
    char* Sc = S0 + (p & 1) * 8192;
    f16x8 bv0, bv1;
    unsigned wfo = (unsigned)((p * 8 + wave) * 1024 + lane * 16);
    GLOADW(bv0, wfo);
    GLOADW(bv1, wfo + 4096);       // queue [g8, wf2] = 10
    asm volatile("s_waitcnt vmcnt(2)" ::: "memory");   // drain g; wf flying
    __builtin_amdgcn_sched_barrier(0);
    BUILD(e, g, Sc);               // consumes g, writes own S slice
    if (p < 8) LOADC(p + 1, e);    // e dead after BUILD — reuse
    // S + coords visible; all waves' MFMA(p-1) LDS reads drained
    asm volatile("s_waitcnt lgkmcnt(0)" ::: "memory");
    __builtin_amdgcn_s_barrier();
    if (p < 8) {
      ISSUE(e, g);                 // queue [wf2, g8] = 10
      asm volatile("s_waitcnt vmcnt(8)" ::: "memory"); // drain wf
    } else {
      asm volatile("s_waitcnt vmcnt(0)" ::: "memory");
    }
    __builtin_amdgcn_sched_barrier(0);
    MFMA(Sc, bv0, bv1);
  }
#undef GLOADX
#undef GLOADW

  // ---- epilogue: LDS transpose for coalesced NCHW stores ----
  __syncthreads();  // all MFMA reads done before overwriting lds as S2
  float* S2 = reinterpret_cast<float*>(lds);
  int l15 = lane & 15;
#pragma unroll
  for (int m = 0; m < 4; ++m) {
#pragma unroll
    for (int i2 = 0; i2 < 4; ++i2) {
      int px = m * 16 + ((lane >> 4) * 4) + i2;
      int o = wave * 16 + l15;
      S2[px * 65 + o] = acc[m][i2];
    }
  }
  __syncthreads();
  {
    int px = t & 63, o2 = t >> 6;
    float* op = out + (((size_t)b * OO) * HH + h) * WW + w0 + px;
#pragma unroll
    for (int o4 = 0; o4 < 16; ++o4) {
      int o = o4 * 4 + o2;
      op[(size_t)o * HH * WW] = S2[px * 65 + o] + bias[o];
    }
  }
}

// ---------------------------------------------------------------------------
extern "C" void kernel_launch(void* const* d_in, const int* in_sizes, int n_in,
                              void* d_out, int out_size, void* d_ws, size_t ws_size,
                              hipStream_t stream) {
  const float* x = (const float*)d_in[0];
  const float* offset = (const float*)d_in[1];
  const float* weight = (const float*)d_in[2];
  const float* bias = (const float*)d_in[3];
  float* out = (float*)d_out;

  unsigned short* xt = (unsigned short*)d_ws;                       // 17,305,600 B
  unsigned short* wf = (unsigned short*)((char*)d_ws + 17305600);   //     73,728 B

  k_xpose<<<BB * HH, 256, 0, stream>>>(x, xt);
  k_wfrag<<<144, 256, 0, stream>>>(weight, wf);
  k_deform_main<<<BB * HH * 2, 256, 0, stream>>>(offset, bias, xt, wf, out);
}